// Round 1
// baseline (976.388 us; speedup 1.0000x reference)
//
#include <hip/hip_runtime.h>

#define NTOK 64
#define DIM 192
#define HD 32

// LDS strides (bf16 elems):
//   RS=200 (100 dw == 4 mod 32): b128 reads 8 dw/bank; b64 writes 4 dw/bank.
//   VTS=68 (34 dw == 2 mod 32): b128 reads (2r+4q+p) 8 dw/bank; b64 writes 4 dw/bank.
// LDS total = 64*200*2 + 192*68*2 = 51712 B -> 3 blocks/CU (was 77312 -> 2).
#define RS  200
#define VTS 68
#define WQN (576 * DIM)
#define WPN (DIM * DIM)

typedef __attribute__((ext_vector_type(8))) short short8;
typedef __attribute__((ext_vector_type(4))) float floatx4;
typedef __attribute__((ext_vector_type(2))) unsigned int uint2v;

__device__ __forceinline__ short f2bf(float f) {
    union { float f; unsigned int u; } c; c.f = f;
    unsigned int r = (c.u + 0x7FFFu + ((c.u >> 16) & 1u)) >> 16;
    return (short)(unsigned short)r;
}

// pack two fp32 -> two bf16 (RNE) in one dword: low16=bf(a), high16=bf(b)
__device__ __forceinline__ unsigned pkbf(float a, float b) {
    unsigned ua = __float_as_uint(a); ua += 0x7FFFu + ((ua >> 16) & 1u);
    unsigned ub = __float_as_uint(b); ub += 0x7FFFu + ((ub >> 16) & 1u);
    return __builtin_amdgcn_perm(ub, ua, 0x07060302u);
}

// 8 consecutive fp32 (16B-aligned) -> bf16x8 fragment (ascending k order)
__device__ __forceinline__ short8 cvt8(const float* p) {
    const float4* v = reinterpret_cast<const float4*>(p);
    float4 lo = v[0], hi = v[1];
    union { unsigned u[4]; short8 s; } r;
    r.u[0] = pkbf(lo.x, lo.y);
    r.u[1] = pkbf(lo.z, lo.w);
    r.u[2] = pkbf(hi.x, hi.y);
    r.u[3] = pkbf(hi.z, hi.w);
    return r.s;
}

// Quad-exchange: two MFMA-D-layout fp32 tiles (v0: rows 0..15, v1: rows 16..31;
// row = 16t + 4*quad + g, col = lane&15) -> bf16 A/B-fragment for K=32:
// lane (r,q) receives rows 8q+j (j=0..7), col r.
//   dword d holds rows 8q+2d,+1: source tile t = q>>1, source quad = 2(q&1)+(d>>1),
//   source g-pair = d&1.  8 ds_bpermute + 4 cndmask, no LDS.
__device__ __forceinline__ short8 qshuf(floatx4 v0, floatx4 v1, int lane) {
    const int q = lane >> 4;
    const unsigned p0a = pkbf(v0[0], v0[1]);   // t=0, g={0,1}
    const unsigned p0b = pkbf(v0[2], v0[3]);   // t=0, g={2,3}
    const unsigned p1a = pkbf(v1[0], v1[1]);   // t=1, g={0,1}
    const unsigned p1b = pkbf(v1[2], v1[3]);   // t=1, g={2,3}
    const int s0 = (lane & 15) | ((q & 1) << 5);   // src quad 2(q&1)   (d=0,1)
    const int s1 = s0 + 16;                        // src quad 2(q&1)+1 (d=2,3)
    const unsigned l0 = (unsigned)__shfl((int)p0a, s0);
    const unsigned h0 = (unsigned)__shfl((int)p1a, s0);
    const unsigned l1 = (unsigned)__shfl((int)p0b, s0);
    const unsigned h1 = (unsigned)__shfl((int)p1b, s0);
    const unsigned l2 = (unsigned)__shfl((int)p0a, s1);
    const unsigned h2 = (unsigned)__shfl((int)p1a, s1);
    const unsigned l3 = (unsigned)__shfl((int)p0b, s1);
    const unsigned h3 = (unsigned)__shfl((int)p1b, s1);
    const bool hi = q >= 2;                        // tile select t = q>>1
    union { unsigned u[4]; short8 s; } ret;
    ret.u[0] = hi ? h0 : l0;
    ret.u[1] = hi ? h1 : l1;
    ret.u[2] = hi ? h2 : l2;
    ret.u[3] = hi ? h3 : l3;
    return ret.s;
}

// One-time (per launch) fp32 -> bf16 weight conversion into workspace.
// Q rows (0..191) of wqkv get the 1/sqrt(32) scale folded in.
__global__ void wprep(const float* __restrict__ wqkv, const float* __restrict__ wproj,
                      short* __restrict__ wqb, short* __restrict__ wpb) {
    const int i = blockIdx.x * 256 + (int)threadIdx.x;
    for (int e = i; e < WQN; e += 192 * 256) {
        float v = wqkv[e];
        if (e < DIM * DIM) v *= 0.17677669529663688f;
        wqb[e] = f2bf(v);
    }
    for (int e = i; e < WPN; e += 192 * 256) wpb[e] = f2bf(wproj[e]);
}

template <int WS>
__global__ __launch_bounds__(256, 3)
void wattn_fused(const float* __restrict__ x, const float* __restrict__ mask,
                 const float* __restrict__ wqkv, const float* __restrict__ wproj,
                 const float* __restrict__ bproj, float* __restrict__ out,
                 const short* __restrict__ wqb, const short* __restrict__ wpb) {
    __shared__ short ksm[NTOK * RS];   // K [token][kdim]; reused for O after attention
    __shared__ short vsT[DIM * VTS];   // V^T [vdim][token]

    const int bw   = blockIdx.x;
    const int tid  = (int)threadIdx.x;
    const int wave = tid >> 6;
    const int lane = tid & 63;
    const int r    = lane & 15;
    const int q    = lane >> 4;

    const float* xb = x + (size_t)bw * (NTOK * DIM);

    auto ldq = [&](int off) -> short8 {      // wqkv fragment (bf16 ws or fp32+cvt)
        if constexpr (WS) return *reinterpret_cast<const short8*>(wqb + off);
        else              return cvt8(wqkv + off);
    };
    auto ldp = [&](int off) -> short8 {      // wproj fragment
        if constexpr (WS) return *reinterpret_cast<const short8*>(wpb + off);
        else              return cvt8(wproj + off);
    };

    // X fragments: A/B-frag layout, lane r = token, k = s*32 + q*8 + j
    short8 a[4][6];
    #pragma unroll
    for (int mt = 0; mt < 4; ++mt) {
        #pragma unroll
        for (int s = 0; s < 6; ++s)
            a[mt][s] = cvt8(xb + (mt * 16 + r) * DIM + s * 32 + q * 8);
    }

    // ---------------- Phase 1a: K (waves 0,1) / V (waves 2,3) -> LDS ----------------
    if (wave < 2) {
        const int cb = wave * 96;
        #pragma unroll
        for (int nt = 0; nt < 6; ++nt) {
            const int dk = cb + nt * 16;
            floatx4 acc[4];
            #pragma unroll
            for (int mt = 0; mt < 4; ++mt) acc[mt] = (floatx4){0.f, 0.f, 0.f, 0.f};
            #pragma unroll
            for (int s = 0; s < 6; ++s) {
                const short8 b8 = ldq((DIM + dk + r) * DIM + s * 32 + q * 8);
                #pragma unroll
                for (int mt = 0; mt < 4; ++mt)  // swapped: D col=token, row=kdim
                    acc[mt] = __builtin_amdgcn_mfma_f32_16x16x32_bf16(b8, a[mt][s], acc[mt], 0, 0, 0);
            }
            #pragma unroll
            for (int mt = 0; mt < 4; ++mt) {    // 4 consecutive kdims -> one b64 store
                uint2v u;
                u.x = pkbf(acc[mt][0], acc[mt][1]);
                u.y = pkbf(acc[mt][2], acc[mt][3]);
                *reinterpret_cast<uint2v*>(ksm + (mt * 16 + r) * RS + dk + q * 4) = u;
            }
        }
    } else {
        const int cb = (wave - 2) * 96;
        #pragma unroll
        for (int nt = 0; nt < 6; ++nt) {
            const int dv = cb + nt * 16;
            floatx4 acc[4];
            #pragma unroll
            for (int mt = 0; mt < 4; ++mt) acc[mt] = (floatx4){0.f, 0.f, 0.f, 0.f};
            #pragma unroll
            for (int s = 0; s < 6; ++s) {
                const short8 b8 = ldq((2 * DIM + dv + r) * DIM + s * 32 + q * 8);
                #pragma unroll
                for (int mt = 0; mt < 4; ++mt)  // normal: D col=vdim, row=token
                    acc[mt] = __builtin_amdgcn_mfma_f32_16x16x32_bf16(a[mt][s], b8, acc[mt], 0, 0, 0);
            }
            #pragma unroll
            for (int mt = 0; mt < 4; ++mt) {    // 4 consecutive tokens -> one b64 store
                uint2v u;
                u.x = pkbf(acc[mt][0], acc[mt][1]);
                u.y = pkbf(acc[mt][2], acc[mt][3]);
                *reinterpret_cast<uint2v*>(vsT + (dv + r) * VTS + mt * 16 + q * 4) = u;
            }
        }
    }

    // ---------------- Phase 1b: per-unit Q -> registers (no LDS) ----------------
    // Unit uu = wave*3+i = (head h = uu>>1, query-half = uu&1). Each wave computes
    // exactly the Q tiles its own units need (72 MFMA/wave; no sharing needed).
    short8 bq[3][2];
    #pragma unroll
    for (int i = 0; i < 3; ++i) {
        const int uu = wave * 3 + i, h = uu >> 1, half = uu & 1;
        floatx4 qa[2][2];                       // [dim-subtile dt][query-tile qt]
        #pragma unroll
        for (int dt = 0; dt < 2; ++dt) {
            #pragma unroll
            for (int qt = 0; qt < 2; ++qt) qa[dt][qt] = (floatx4){0.f, 0.f, 0.f, 0.f};
        }
        #pragma unroll
        for (int s = 0; s < 6; ++s) {
            const short8 w0 = ldq((h * HD + r) * DIM + s * 32 + q * 8);
            const short8 w1 = ldq((h * HD + 16 + r) * DIM + s * 32 + q * 8);
            #pragma unroll
            for (int qt = 0; qt < 2; ++qt) {    // swapped: D col=token, row=qdim
                qa[0][qt] = __builtin_amdgcn_mfma_f32_16x16x32_bf16(w0, a[half * 2 + qt][s], qa[0][qt], 0, 0, 0);
                qa[1][qt] = __builtin_amdgcn_mfma_f32_16x16x32_bf16(w1, a[half * 2 + qt][s], qa[1][qt], 0, 0, 0);
            }
        }
        if constexpr (!WS) {                    // scale folded into weights when WS
            #pragma unroll
            for (int dt = 0; dt < 2; ++dt)
                #pragma unroll
                for (int qt = 0; qt < 2; ++qt)
                    #pragma unroll
                    for (int g = 0; g < 4; ++g)
                        qa[dt][qt][g] *= 0.17677669529663688f;
        }
        bq[i][0] = qshuf(qa[0][0], qa[1][0], lane);  // lane r=query, k=head dim
        bq[i][1] = qshuf(qa[0][1], qa[1][1], lane);
    }
    __syncthreads();

    // ---------------- Phase 2: attention, fully in registers ----------------
    const float* mb  = mask + (size_t)bw * (NTOK * NTOK);
    const float* mbl = mb + 256 * q + r;   // mask is symmetric: read [key][query] (coalesced)
    uint2v obf[3][2][2];                   // O as packed bf16, written to LDS post-barrier

    #pragma unroll
    for (int i = 0; i < 3; ++i) {
        const int uu = wave * 3 + i, h = uu >> 1, half = uu & 1;

        // mask loads issued early (HBM latency hides under LDS reads + MFMA)
        float mv[2][4][4];
        #pragma unroll
        for (int qt = 0; qt < 2; ++qt)
            #pragma unroll
            for (int kt = 0; kt < 4; ++kt)
                #pragma unroll
                for (int g = 0; g < 4; ++g)
                    mv[qt][kt][g] = mbl[kt * 1024 + g * 64 + half * 32 + qt * 16];

        short8 bk[4];
        #pragma unroll
        for (int kt = 0; kt < 4; ++kt)
            bk[kt] = *reinterpret_cast<const short8*>(ksm + (kt * 16 + r) * RS + h * HD + q * 8);

        // S^T = mfma(K, Q): lane col=query (r), row=key (kt*16 + q*4+g)
        floatx4 sa[4][2];
        #pragma unroll
        for (int kt = 0; kt < 4; ++kt) {
            #pragma unroll
            for (int qt = 0; qt < 2; ++qt) {
                floatx4 z = (floatx4){0.f, 0.f, 0.f, 0.f};
                sa[kt][qt] = __builtin_amdgcn_mfma_f32_16x16x32_bf16(bk[kt], bq[i][qt], z, 0, 0, 0);
            }
        }
        #pragma unroll
        for (int kt = 0; kt < 4; ++kt)
            #pragma unroll
            for (int qt = 0; qt < 2; ++qt)
                #pragma unroll
                for (int g = 0; g < 4; ++g)
                    sa[kt][qt][g] += mv[qt][kt][g];

        // softmax: 16 in-lane values + 2 cross-quad shuffles (keys live on quads)
        float rinv[2];
        #pragma unroll
        for (int qt = 0; qt < 2; ++qt) {
            float mx = sa[0][qt][0];
            #pragma unroll
            for (int kt = 0; kt < 4; ++kt)
                #pragma unroll
                for (int g = 0; g < 4; ++g) mx = fmaxf(mx, sa[kt][qt][g]);
            mx = fmaxf(mx, __shfl_xor(mx, 16));
            mx = fmaxf(mx, __shfl_xor(mx, 32));
            float sm = 0.f;
            #pragma unroll
            for (int kt = 0; kt < 4; ++kt) {
                #pragma unroll
                for (int g = 0; g < 4; ++g) {
                    float p = __expf(sa[kt][qt][g] - mx);
                    sa[kt][qt][g] = p;
                    sm += p;
                }
            }
            sm += __shfl_xor(sm, 16);
            sm += __shfl_xor(sm, 32);
            rinv[qt] = 1.0f / sm;              // normalization deferred to O
        }

        // P fragments in-register (no LDS round-trip)
        short8 ap[2][2];
        #pragma unroll
        for (int qt = 0; qt < 2; ++qt) {
            #pragma unroll
            for (int kk = 0; kk < 2; ++kk)
                ap[qt][kk] = qshuf(sa[2 * kk][qt], sa[2 * kk + 1][qt], lane);
        }

        short8 bv[2][2];
        #pragma unroll
        for (int nv = 0; nv < 2; ++nv)
            #pragma unroll
            for (int kk = 0; kk < 2; ++kk)
                bv[nv][kk] = *reinterpret_cast<const short8*>(
                    vsT + (h * HD + nv * 16 + r) * VTS + kk * 32 + q * 8);

        // O^T = mfma(V^T, P^T): lane col=query (r) -> rinv is lane-local
        #pragma unroll
        for (int qt = 0; qt < 2; ++qt) {
            #pragma unroll
            for (int nv = 0; nv < 2; ++nv) {
                floatx4 o = (floatx4){0.f, 0.f, 0.f, 0.f};
                o = __builtin_amdgcn_mfma_f32_16x16x32_bf16(bv[nv][0], ap[qt][0], o, 0, 0, 0);
                o = __builtin_amdgcn_mfma_f32_16x16x32_bf16(bv[nv][1], ap[qt][1], o, 0, 0, 0);
                uint2v u;
                u.x = pkbf(o[0] * rinv[qt], o[1] * rinv[qt]);
                u.y = pkbf(o[2] * rinv[qt], o[3] * rinv[qt]);
                obf[i][qt][nv] = u;
            }
        }
    }

    __syncthreads();   // all K/V LDS reads done -> safe to overwrite ksm with O
    #pragma unroll
    for (int i = 0; i < 3; ++i) {
        const int uu = wave * 3 + i, h = uu >> 1, half = uu & 1;
        #pragma unroll
        for (int qt = 0; qt < 2; ++qt)
            #pragma unroll
            for (int nv = 0; nv < 2; ++nv)
                *reinterpret_cast<uint2v*>(
                    ksm + (half * 32 + qt * 16 + r) * RS + h * HD + nv * 16 + q * 4) = obf[i][qt][nv];
    }
    __syncthreads();

    // ---------------- Phase 3: out = O * Wproj^T + b ----------------
    short8 ao[4][6];
    #pragma unroll
    for (int mt = 0; mt < 4; ++mt) {
        #pragma unroll
        for (int s = 0; s < 6; ++s)
            ao[mt][s] = *reinterpret_cast<const short8*>(ksm + (mt * 16 + r) * RS + s * 32 + q * 8);
    }

    float* ob = out + (size_t)bw * (NTOK * DIM);
    const int D0 = wave * 48;
    #pragma unroll
    for (int nt = 0; nt < 3; ++nt) {
        const int d0 = D0 + nt * 16;
        const float4 b4 = *reinterpret_cast<const float4*>(bproj + d0 + q * 4);
        floatx4 acc[4];
        #pragma unroll
        for (int mt = 0; mt < 4; ++mt) acc[mt] = (floatx4){b4.x, b4.y, b4.z, b4.w};
        #pragma unroll
        for (int s = 0; s < 6; ++s) {
            const short8 w8 = ldp((d0 + r) * DIM + s * 32 + q * 8);
            #pragma unroll
            for (int mt = 0; mt < 4; ++mt)      // swapped: D col=token, row=outdim
                acc[mt] = __builtin_amdgcn_mfma_f32_16x16x32_bf16(w8, ao[mt][s], acc[mt], 0, 0, 0);
        }
        #pragma unroll
        for (int mt = 0; mt < 4; ++mt) {        // 4 consecutive dims -> float4 store
            float4 st;
            st.x = acc[mt][0]; st.y = acc[mt][1]; st.z = acc[mt][2]; st.w = acc[mt][3];
            *reinterpret_cast<float4*>(ob + (mt * 16 + r) * DIM + d0 + q * 4) = st;
        }
    }
}

extern "C" void kernel_launch(void* const* d_in, const int* in_sizes, int n_in,
                              void* d_out, int out_size, void* d_ws, size_t ws_size,
                              hipStream_t stream) {
    const float* x    = (const float*)d_in[0];
    const float* mask = (const float*)d_in[1];
    const float* wqkv = (const float*)d_in[2];
    const float* wp   = (const float*)d_in[3];
    const float* bp   = (const float*)d_in[4];
    float* out = (float*)d_out;
    const int nblocks = in_sizes[0] / (NTOK * DIM);  // 4096 windows
    const size_t need = (size_t)(WQN + WPN) * sizeof(short);
    if (d_ws != nullptr && ws_size >= need) {
        short* wqb = (short*)d_ws;
        short* wpb = wqb + WQN;
        wprep<<<192, 256, 0, stream>>>(wqkv, wp, wqb, wpb);
        wattn_fused<1><<<nblocks, 256, 0, stream>>>(x, mask, wqkv, wp, bp, out, wqb, wpb);
    } else {
        wattn_fused<0><<<nblocks, 256, 0, stream>>>(x, mask, wqkv, wp, bp, out, nullptr, nullptr);
    }
}

// Round 2
// 687.252 us; speedup vs baseline: 1.4207x; 1.4207x over previous
//
#include <hip/hip_runtime.h>

#define NTOK 64
#define DIM 192
#define HD 32

// LDS strides (bf16 elems):
//   RS=200 (100 dw == 4 mod 32): b128 reads 8 dw/bank; b64 writes 4 dw/bank.
//   VTS=68 (34 dw == 2 mod 32): b128 reads (2r+4q+p) 8 dw/bank; b64 writes 4 dw/bank.
// LDS total = 64*200*2 + 192*68*2 = 51712 B -> 3 blocks/CU.
#define RS  200
#define VTS 68
#define WQN (576 * DIM)
#define WPN (DIM * DIM)

typedef __attribute__((ext_vector_type(8))) short short8;
typedef __attribute__((ext_vector_type(4))) float floatx4;
typedef __attribute__((ext_vector_type(2))) unsigned int uint2v;

__device__ __forceinline__ short f2bf(float f) {
    union { float f; unsigned int u; } c; c.f = f;
    unsigned int r = (c.u + 0x7FFFu + ((c.u >> 16) & 1u)) >> 16;
    return (short)(unsigned short)r;
}

// pack two fp32 -> two bf16 (RNE) in one dword: low16=bf(a), high16=bf(b)
__device__ __forceinline__ unsigned pkbf(float a, float b) {
    unsigned ua = __float_as_uint(a); ua += 0x7FFFu + ((ua >> 16) & 1u);
    unsigned ub = __float_as_uint(b); ub += 0x7FFFu + ((ub >> 16) & 1u);
    return __builtin_amdgcn_perm(ub, ua, 0x07060302u);
}

// 8 consecutive fp32 (16B-aligned) -> bf16x8 fragment (ascending k order)
__device__ __forceinline__ short8 cvt8(const float* p) {
    const float4* v = reinterpret_cast<const float4*>(p);
    float4 lo = v[0], hi = v[1];
    union { unsigned u[4]; short8 s; } r;
    r.u[0] = pkbf(lo.x, lo.y);
    r.u[1] = pkbf(lo.z, lo.w);
    r.u[2] = pkbf(hi.x, hi.y);
    r.u[3] = pkbf(hi.z, hi.w);
    return r.s;
}

// Quad-exchange: two MFMA-D-layout fp32 tiles (v0: rows 0..15, v1: rows 16..31;
// row = 16t + 4*quad + g, col = lane&15) -> bf16 A/B-fragment for K=32:
// lane (r,q) receives rows 8q+j (j=0..7), col r.
__device__ __forceinline__ short8 qshuf(floatx4 v0, floatx4 v1, int lane) {
    const int q = lane >> 4;
    const unsigned p0a = pkbf(v0[0], v0[1]);   // t=0, g={0,1}
    const unsigned p0b = pkbf(v0[2], v0[3]);   // t=0, g={2,3}
    const unsigned p1a = pkbf(v1[0], v1[1]);   // t=1, g={0,1}
    const unsigned p1b = pkbf(v1[2], v1[3]);   // t=1, g={2,3}
    const int s0 = (lane & 15) | ((q & 1) << 5);   // src quad 2(q&1)   (d=0,1)
    const int s1 = s0 + 16;                        // src quad 2(q&1)+1 (d=2,3)
    const unsigned l0 = (unsigned)__shfl((int)p0a, s0);
    const unsigned h0 = (unsigned)__shfl((int)p1a, s0);
    const unsigned l1 = (unsigned)__shfl((int)p0b, s0);
    const unsigned h1 = (unsigned)__shfl((int)p1b, s0);
    const unsigned l2 = (unsigned)__shfl((int)p0a, s1);
    const unsigned h2 = (unsigned)__shfl((int)p1a, s1);
    const unsigned l3 = (unsigned)__shfl((int)p0b, s1);
    const unsigned h3 = (unsigned)__shfl((int)p1b, s1);
    const bool hi = q >= 2;                        // tile select t = q>>1
    union { unsigned u[4]; short8 s; } ret;
    ret.u[0] = hi ? h0 : l0;
    ret.u[1] = hi ? h1 : l1;
    ret.u[2] = hi ? h2 : l2;
    ret.u[3] = hi ? h3 : l3;
    return ret.s;
}

// One-time (per launch) fp32 -> bf16 weight conversion into workspace.
// Q rows (0..191) of wqkv get the 1/sqrt(32) scale folded in.
__global__ void wprep(const float* __restrict__ wqkv, const float* __restrict__ wproj,
                      short* __restrict__ wqb, short* __restrict__ wpb) {
    const int i = blockIdx.x * 256 + (int)threadIdx.x;
    for (int e = i; e < WQN; e += 192 * 256) {
        float v = wqkv[e];
        if (e < DIM * DIM) v *= 0.17677669529663688f;
        wqb[e] = f2bf(v);
    }
    for (int e = i; e < WPN; e += 192 * 256) wpb[e] = f2bf(wproj[e]);
}

template <int WS>
__global__ __launch_bounds__(256, 3)
void wattn_fused(const float* __restrict__ x, const float* __restrict__ mask,
                 const float* __restrict__ wqkv, const float* __restrict__ wproj,
                 const float* __restrict__ bproj, float* __restrict__ out,
                 const short* __restrict__ wqb, const short* __restrict__ wpb) {
    __shared__ short ksm[NTOK * RS];   // K [token][kdim]; reused for O after attention
    __shared__ short vsT[DIM * VTS];   // V^T [vdim][token]

    const int bw   = blockIdx.x;
    const int tid  = (int)threadIdx.x;
    const int wave = tid >> 6;
    const int lane = tid & 63;
    const int r    = lane & 15;
    const int q    = lane >> 4;

    const float* xb = x + (size_t)bw * (NTOK * DIM);

    auto ldq = [&](int off) -> short8 {      // wqkv fragment (bf16 ws or fp32+cvt)
        if constexpr (WS) return *reinterpret_cast<const short8*>(wqb + off);
        else              return cvt8(wqkv + off);
    };
    auto ldp = [&](int off) -> short8 {      // wproj fragment
        if constexpr (WS) return *reinterpret_cast<const short8*>(wpb + off);
        else              return cvt8(wproj + off);
    };

    // ---------------- Phase 1a: K (waves 0,1) / V (waves 2,3) -> LDS ----------------
    // X fragments live ONLY in this scope (96 VGPRs; keeping them live into
    // phase 1b spilled them to scratch last round: +1.7 GB HBM traffic).
    {
        short8 a[4][6];   // A/B-frag layout, lane r = token, k = s*32 + q*8 + j
        #pragma unroll
        for (int mt = 0; mt < 4; ++mt) {
            #pragma unroll
            for (int s = 0; s < 6; ++s)
                a[mt][s] = cvt8(xb + (mt * 16 + r) * DIM + s * 32 + q * 8);
        }

        if (wave < 2) {
            const int cb = wave * 96;
            #pragma unroll
            for (int nt = 0; nt < 6; ++nt) {
                const int dk = cb + nt * 16;
                floatx4 acc[4];
                #pragma unroll
                for (int mt = 0; mt < 4; ++mt) acc[mt] = (floatx4){0.f, 0.f, 0.f, 0.f};
                #pragma unroll
                for (int s = 0; s < 6; ++s) {
                    const short8 b8 = ldq((DIM + dk + r) * DIM + s * 32 + q * 8);
                    #pragma unroll
                    for (int mt = 0; mt < 4; ++mt)  // swapped: D col=token, row=kdim
                        acc[mt] = __builtin_amdgcn_mfma_f32_16x16x32_bf16(b8, a[mt][s], acc[mt], 0, 0, 0);
                }
                #pragma unroll
                for (int mt = 0; mt < 4; ++mt) {    // 4 consecutive kdims -> one b64 store
                    uint2v u;
                    u.x = pkbf(acc[mt][0], acc[mt][1]);
                    u.y = pkbf(acc[mt][2], acc[mt][3]);
                    *reinterpret_cast<uint2v*>(ksm + (mt * 16 + r) * RS + dk + q * 4) = u;
                }
            }
        } else {
            const int cb = (wave - 2) * 96;
            #pragma unroll
            for (int nt = 0; nt < 6; ++nt) {
                const int dv = cb + nt * 16;
                floatx4 acc[4];
                #pragma unroll
                for (int mt = 0; mt < 4; ++mt) acc[mt] = (floatx4){0.f, 0.f, 0.f, 0.f};
                #pragma unroll
                for (int s = 0; s < 6; ++s) {
                    const short8 b8 = ldq((2 * DIM + dv + r) * DIM + s * 32 + q * 8);
                    #pragma unroll
                    for (int mt = 0; mt < 4; ++mt)  // normal: D col=vdim, row=token
                        acc[mt] = __builtin_amdgcn_mfma_f32_16x16x32_bf16(a[mt][s], b8, acc[mt], 0, 0, 0);
                }
                #pragma unroll
                for (int mt = 0; mt < 4; ++mt) {    // 4 consecutive tokens -> one b64 store
                    uint2v u;
                    u.x = pkbf(acc[mt][0], acc[mt][1]);
                    u.y = pkbf(acc[mt][2], acc[mt][3]);
                    *reinterpret_cast<uint2v*>(vsT + (dv + r) * VTS + mt * 16 + q * 4) = u;
                }
            }
        }
    }
    // Pin: nothing from phase 1b may hoist above this point (would stretch
    // live ranges back across phase 1a and re-create the spill).
    __builtin_amdgcn_sched_barrier(0);

    // ---------------- Phase 1b: per-unit Q -> registers (no LDS) ----------------
    // Unit uu = wave*3+i = (head h = uu>>1, query-half = uu&1). X fragments are
    // re-fetched from global (L1/L2-hot, 32 B each) instead of kept live.
    short8 bq[3][2];
    #pragma unroll
    for (int i = 0; i < 3; ++i) {
        const int uu = wave * 3 + i, h = uu >> 1, half = uu & 1;
        floatx4 qa[2][2];                       // [dim-subtile dt][query-tile qt]
        #pragma unroll
        for (int dt = 0; dt < 2; ++dt) {
            #pragma unroll
            for (int qt = 0; qt < 2; ++qt) qa[dt][qt] = (floatx4){0.f, 0.f, 0.f, 0.f};
        }
        #pragma unroll
        for (int s = 0; s < 6; ++s) {
            const short8 w0 = ldq((h * HD + r) * DIM + s * 32 + q * 8);
            const short8 w1 = ldq((h * HD + 16 + r) * DIM + s * 32 + q * 8);
            #pragma unroll
            for (int qt = 0; qt < 2; ++qt) {    // swapped: D col=token, row=qdim
                const short8 xf = cvt8(xb + ((half * 2 + qt) * 16 + r) * DIM + s * 32 + q * 8);
                qa[0][qt] = __builtin_amdgcn_mfma_f32_16x16x32_bf16(w0, xf, qa[0][qt], 0, 0, 0);
                qa[1][qt] = __builtin_amdgcn_mfma_f32_16x16x32_bf16(w1, xf, qa[1][qt], 0, 0, 0);
            }
        }
        if constexpr (!WS) {                    // scale folded into weights when WS
            #pragma unroll
            for (int dt = 0; dt < 2; ++dt)
                #pragma unroll
                for (int qt = 0; qt < 2; ++qt)
                    #pragma unroll
                    for (int g = 0; g < 4; ++g)
                        qa[dt][qt][g] *= 0.17677669529663688f;
        }
        bq[i][0] = qshuf(qa[0][0], qa[1][0], lane);  // lane r=query, k=head dim
        bq[i][1] = qshuf(qa[0][1], qa[1][1], lane);
    }
    __syncthreads();

    // ---------------- Phase 2: attention, fully in registers ----------------
    const float* mb  = mask + (size_t)bw * (NTOK * NTOK);
    const float* mbl = mb + 256 * q + r;   // mask is symmetric: read [key][query] (coalesced)
    uint2v obf[3][2][2];                   // O as packed bf16, written to LDS post-barrier

    #pragma unroll
    for (int i = 0; i < 3; ++i) {
        const int uu = wave * 3 + i, h = uu >> 1, half = uu & 1;

        // mask loads issued early (HBM latency hides under LDS reads + MFMA)
        float mv[2][4][4];
        #pragma unroll
        for (int qt = 0; qt < 2; ++qt)
            #pragma unroll
            for (int kt = 0; kt < 4; ++kt)
                #pragma unroll
                for (int g = 0; g < 4; ++g)
                    mv[qt][kt][g] = mbl[kt * 1024 + g * 64 + half * 32 + qt * 16];

        short8 bk[4];
        #pragma unroll
        for (int kt = 0; kt < 4; ++kt)
            bk[kt] = *reinterpret_cast<const short8*>(ksm + (kt * 16 + r) * RS + h * HD + q * 8);

        // S^T = mfma(K, Q): lane col=query (r), row=key (kt*16 + q*4+g)
        floatx4 sa[4][2];
        #pragma unroll
        for (int kt = 0; kt < 4; ++kt) {
            #pragma unroll
            for (int qt = 0; qt < 2; ++qt) {
                floatx4 z = (floatx4){0.f, 0.f, 0.f, 0.f};
                sa[kt][qt] = __builtin_amdgcn_mfma_f32_16x16x32_bf16(bk[kt], bq[i][qt], z, 0, 0, 0);
            }
        }
        #pragma unroll
        for (int kt = 0; kt < 4; ++kt)
            #pragma unroll
            for (int qt = 0; qt < 2; ++qt)
                #pragma unroll
                for (int g = 0; g < 4; ++g)
                    sa[kt][qt][g] += mv[qt][kt][g];

        // softmax: 16 in-lane values + 2 cross-quad shuffles (keys live on quads)
        float rinv[2];
        #pragma unroll
        for (int qt = 0; qt < 2; ++qt) {
            float mx = sa[0][qt][0];
            #pragma unroll
            for (int kt = 0; kt < 4; ++kt)
                #pragma unroll
                for (int g = 0; g < 4; ++g) mx = fmaxf(mx, sa[kt][qt][g]);
            mx = fmaxf(mx, __shfl_xor(mx, 16));
            mx = fmaxf(mx, __shfl_xor(mx, 32));
            float sm = 0.f;
            #pragma unroll
            for (int kt = 0; kt < 4; ++kt) {
                #pragma unroll
                for (int g = 0; g < 4; ++g) {
                    float p = __expf(sa[kt][qt][g] - mx);
                    sa[kt][qt][g] = p;
                    sm += p;
                }
            }
            sm += __shfl_xor(sm, 16);
            sm += __shfl_xor(sm, 32);
            rinv[qt] = 1.0f / sm;              // normalization deferred to O
        }

        // P fragments in-register (no LDS round-trip)
        short8 ap[2][2];
        #pragma unroll
        for (int qt = 0; qt < 2; ++qt) {
            #pragma unroll
            for (int kk = 0; kk < 2; ++kk)
                ap[qt][kk] = qshuf(sa[2 * kk][qt], sa[2 * kk + 1][qt], lane);
        }

        short8 bv[2][2];
        #pragma unroll
        for (int nv = 0; nv < 2; ++nv)
            #pragma unroll
            for (int kk = 0; kk < 2; ++kk)
                bv[nv][kk] = *reinterpret_cast<const short8*>(
                    vsT + (h * HD + nv * 16 + r) * VTS + kk * 32 + q * 8);

        // O^T = mfma(V^T, P^T): lane col=query (r) -> rinv is lane-local
        #pragma unroll
        for (int qt = 0; qt < 2; ++qt) {
            #pragma unroll
            for (int nv = 0; nv < 2; ++nv) {
                floatx4 o = (floatx4){0.f, 0.f, 0.f, 0.f};
                o = __builtin_amdgcn_mfma_f32_16x16x32_bf16(bv[nv][0], ap[qt][0], o, 0, 0, 0);
                o = __builtin_amdgcn_mfma_f32_16x16x32_bf16(bv[nv][1], ap[qt][1], o, 0, 0, 0);
                uint2v u;
                u.x = pkbf(o[0] * rinv[qt], o[1] * rinv[qt]);
                u.y = pkbf(o[2] * rinv[qt], o[3] * rinv[qt]);
                obf[i][qt][nv] = u;
            }
        }
    }

    __syncthreads();   // all K/V LDS reads done -> safe to overwrite ksm with O
    #pragma unroll
    for (int i = 0; i < 3; ++i) {
        const int uu = wave * 3 + i, h = uu >> 1, half = uu & 1;
        #pragma unroll
        for (int qt = 0; qt < 2; ++qt)
            #pragma unroll
            for (int nv = 0; nv < 2; ++nv)
                *reinterpret_cast<uint2v*>(
                    ksm + (half * 32 + qt * 16 + r) * RS + h * HD + nv * 16 + q * 4) = obf[i][qt][nv];
    }
    __syncthreads();

    // ---------------- Phase 3: out = O * Wproj^T + b ----------------
    short8 ao[4][6];
    #pragma unroll
    for (int mt = 0; mt < 4; ++mt) {
        #pragma unroll
        for (int s = 0; s < 6; ++s)
            ao[mt][s] = *reinterpret_cast<const short8*>(ksm + (mt * 16 + r) * RS + s * 32 + q * 8);
    }

    float* ob = out + (size_t)bw * (NTOK * DIM);
    const int D0 = wave * 48;
    #pragma unroll
    for (int nt = 0; nt < 3; ++nt) {
        const int d0 = D0 + nt * 16;
        const float4 b4 = *reinterpret_cast<const float4*>(bproj + d0 + q * 4);
        floatx4 acc[4];
        #pragma unroll
        for (int mt = 0; mt < 4; ++mt) acc[mt] = (floatx4){b4.x, b4.y, b4.z, b4.w};
        #pragma unroll
        for (int s = 0; s < 6; ++s) {
            const short8 w8 = ldp((d0 + r) * DIM + s * 32 + q * 8);
            #pragma unroll
            for (int mt = 0; mt < 4; ++mt)      // swapped: D col=token, row=outdim
                acc[mt] = __builtin_amdgcn_mfma_f32_16x16x32_bf16(w8, ao[mt][s], acc[mt], 0, 0, 0);
        }
        #pragma unroll
        for (int mt = 0; mt < 4; ++mt) {        // 4 consecutive dims -> float4 store
            float4 st;
            st.x = acc[mt][0]; st.y = acc[mt][1]; st.z = acc[mt][2]; st.w = acc[mt][3];
            *reinterpret_cast<float4*>(ob + (mt * 16 + r) * DIM + d0 + q * 4) = st;
        }
    }
}

extern "C" void kernel_launch(void* const* d_in, const int* in_sizes, int n_in,
                              void* d_out, int out_size, void* d_ws, size_t ws_size,
                              hipStream_t stream) {
    const float* x    = (const float*)d_in[0];
    const float* mask = (const float*)d_in[1];
    const float* wqkv = (const float*)d_in[2];
    const float* wp   = (const float*)d_in[3];
    const float* bp   = (const float*)d_in[4];
    float* out = (float*)d_out;
    const int nblocks = in_sizes[0] / (NTOK * DIM);  // 4096 windows
    const size_t need = (size_t)(WQN + WPN) * sizeof(short);
    if (d_ws != nullptr && ws_size >= need) {
        short* wqb = (short*)d_ws;
        short* wpb = wqb + WQN;
        wprep<<<192, 256, 0, stream>>>(wqkv, wp, wqb, wpb);
        wattn_fused<1><<<nblocks, 256, 0, stream>>>(x, mask, wqkv, wp, bp, out, wqb, wpb);
    } else {
        wattn_fused<0><<<nblocks, 256, 0, stream>>>(x, mask, wqkv, wp, bp, out, nullptr, nullptr);
    }
}